// Round 6
// baseline (423.241 us; speedup 1.0000x reference)
//
#include <hip/hip_runtime.h>
#include <math.h>

#define NN 32768
#define NE 524288

__device__ __forceinline__ float sspf(float x) {
    float r = fmaxf(x, 0.0f) + log1pf(expf(-fabsf(x)));
    return r - 0.69314718055994530942f;
}

// ---------------- CSR build ----------------
__global__ __launch_bounds__(256) void hist_kernel(
    const int* __restrict__ idx_i, int* __restrict__ counts)
{
    int e = blockIdx.x * 256 + threadIdx.x;
    atomicAdd(&counts[idx_i[e]], 1);
}

// single block, 1024 threads, 32 counts each; writes start[0..NN] and cursor
__global__ __launch_bounds__(1024) void scan_kernel(
    const int* __restrict__ counts, int* __restrict__ start, int* __restrict__ cursor)
{
    __shared__ int tmp[1024];
    int tid = threadIdx.x;
    int base = tid * 32;
    int local[32];
    int sum = 0;
    const int4* c4 = (const int4*)(counts + base);
#pragma unroll
    for (int q = 0; q < 8; q++) {
        int4 v = c4[q];
        local[q*4+0] = sum; sum += v.x;
        local[q*4+1] = sum; sum += v.y;
        local[q*4+2] = sum; sum += v.z;
        local[q*4+3] = sum; sum += v.w;
    }
    tmp[tid] = sum;
    __syncthreads();
    for (int off = 1; off < 1024; off <<= 1) {
        int v = 0;
        if (tid >= off) v = tmp[tid - off];
        __syncthreads();
        if (tid >= off) tmp[tid] += v;
        __syncthreads();
    }
    int excl = tmp[tid] - sum;
#pragma unroll
    for (int k = 0; k < 32; k++) {
        int s = excl + local[k];
        start[base + k] = s;
        cursor[base + k] = s;
    }
    if (tid == 1023) start[NN] = tmp[1023];
}

// ---------------- pack: fused fill + filter-MLP-layer-1 ----------------
// record (24 floats): [0:16)=h*rc, [16:20)=Yr, [20]=rc, [21]=j(bits), [22:24)=pad
__global__ __launch_bounds__(256) void pack_kernel(
    const float* __restrict__ f_ij,     // (E,32)
    const float* __restrict__ rcut_ij,  // (E,)
    const float* __restrict__ Yr,       // (E,4)
    const int*   __restrict__ idx_i,
    const int*   __restrict__ idx_j,
    const float* __restrict__ mW1,      // (32,16)
    const float* __restrict__ mb1,      // (16,)
    int* __restrict__ cursor,
    float* __restrict__ epack)
{
    __shared__ float sW1[512];
    __shared__ float sb1[16];
    int t = threadIdx.x;
    for (int k = t; k < 512; k += 256) sW1[k] = mW1[k];
    if (t < 16) sb1[t] = mb1[t];
    __syncthreads();

    int e = blockIdx.x * 256 + t;
    float h[16];
#pragma unroll
    for (int f = 0; f < 16; f++) h[f] = sb1[f];
    const float4* frow = (const float4*)(f_ij + (size_t)e * 32);
#pragma unroll
    for (int rq = 0; rq < 8; rq++) {
        float4 fv = frow[rq];
        int r = rq * 4;
#pragma unroll
        for (int f = 0; f < 16; f++)
            h[f] += fv.x * sW1[(r+0)*16+f] + fv.y * sW1[(r+1)*16+f]
                  + fv.z * sW1[(r+2)*16+f] + fv.w * sW1[(r+3)*16+f];
    }
    float rc = rcut_ij[e];
#pragma unroll
    for (int f = 0; f < 16; f++) h[f] = sspf(h[f]) * rc;

    int i = idx_i[e];
    int j = idx_j[e];
    float4 y = ((const float4*)Yr)[e];
    int slot = atomicAdd(&cursor[i], 1);

    float* rec = epack + (size_t)slot * 24;
    float4* r4 = (float4*)rec;
#pragma unroll
    for (int q = 0; q < 4; q++) r4[q] = ((float4*)h)[q];
    r4[4] = y;
    rec[20] = rc;
    rec[21] = __int_as_float(j);
    rec[22] = 0.f;
    rec[23] = 0.f;
}

// ---------------- node embedding ----------------
// planar output layout: [0:16)=s1, [16:32)=v1x, [32:48)=v1y, [48:64)=v1z
__global__ __launch_bounds__(256) void embed_kernel(
    const float* __restrict__ x,
    const float* __restrict__ W1s,   // (64,16)
    const float* __restrict__ W1v,   // (32,16)
    float* __restrict__ embed)
{
    __shared__ float sWs[1024];
    __shared__ float sWv[512];
    int t = threadIdx.x;
    for (int k = t; k < 1024; k += 256) sWs[k] = W1s[k];
    for (int k = t; k < 512;  k += 256) sWv[k] = W1v[k];
    __syncthreads();

    int n = blockIdx.x * 256 + t;
    const float* xr = x + (size_t)n * 160;

    float s1[16];
#pragma unroll
    for (int f = 0; f < 16; f++) s1[f] = 0.f;
#pragma unroll
    for (int cq = 0; cq < 16; cq++) {
        float4 sv = ((const float4*)xr)[cq];
        int c = cq * 4;
#pragma unroll
        for (int f = 0; f < 16; f++) {
            s1[f] += sv.x * sWs[(c+0)*16+f] + sv.y * sWs[(c+1)*16+f]
                   + sv.z * sWs[(c+2)*16+f] + sv.w * sWs[(c+3)*16+f];
        }
    }

    float v1[48];
#pragma unroll
    for (int k = 0; k < 48; k++) v1[k] = 0.f;
#pragma unroll
    for (int q = 0; q < 24; q++) {
        float4 vv = ((const float4*)(xr + 64))[q];
        float vals[4] = {vv.x, vv.y, vv.z, vv.w};
#pragma unroll
        for (int u = 0; u < 4; u++) {
            int m = q * 4 + u;
            int c = m / 3, d = m % 3;
            float val = vals[u];
#pragma unroll
            for (int f = 0; f < 16; f++)
                v1[f*3+d] += val * sWv[c*16+f];
        }
    }

    float ob[64];
    const float is32 = 0.17677669529663688f;
#pragma unroll
    for (int f = 0; f < 16; f++) {
        ob[f]      = s1[f] * 0.125f;
        ob[16 + f] = v1[f*3+0] * is32;
        ob[32 + f] = v1[f*3+1] * is32;
        ob[48 + f] = v1[f*3+2] * is32;
    }

    float4* eo = (float4*)(embed + (size_t)n * 64);
#pragma unroll
    for (int q = 0; q < 16; q++) eo[q] = ((float4*)ob)[q];
}

// ---------------- node-centric aggregation ----------------
// 16 threads per node; thread handles a single f. w-matmul fully partitioned.
// acc planar layout per node:
// [0:16)=n0a, [16:32)=n0b, [32:48)=n1a_x, [48:64)=n1a_y, [64:80)=n1a_z,
// [80:96)=n1b_x, [96:112)=n1b_y, [112:128)=n1b_z
__global__ __launch_bounds__(256) void nodeagg_kernel(
    const float* __restrict__ embed,   // (N,64) planar
    const float* __restrict__ epack,   // (E,24) CSR-ordered records
    const int*   __restrict__ start,   // (N+1,)
    const float* __restrict__ mW2,     // (16,96)
    const float* __restrict__ mb2,     // (96,)
    float* __restrict__ acc)           // (N,128) planar
{
    __shared__ float sW2[1024];        // sW2[k*64+c] = mW2[k*96+c], c<64
    int t = threadIdx.x;
    for (int k = t; k < 1024; k += 256)
        sW2[k] = mW2[(k >> 6) * 96 + (k & 63)];
    __syncthreads();

    int gid = blockIdx.x * 256 + t;
    int node = gid >> 4;
    int f = gid & 15;

    float wga[16], wgb[16], wgc[16], wgd[16];
#pragma unroll
    for (int k = 0; k < 16; k++) {
        wga[k] = sW2[k*64 + f];
        wgb[k] = sW2[k*64 + 16 + f];
        wgc[k] = sW2[k*64 + 32 + f];
        wgd[k] = sW2[k*64 + 48 + f];
    }
    float b0a = mb2[f], b0b = mb2[16+f], b1a = mb2[32+f], b1b = mb2[48+f];

    float aa = 0.f, ab = 0.f;
    float A1a0 = 0.f, A1a1 = 0.f, A1a2 = 0.f;
    float A1b0 = 0.f, A1b1 = 0.f, A1b2 = 0.f;

    int s0 = start[node];
    int s1 = start[node+1];

    for (int q = s0; q < s1; q++) {
        const float* rec = epack + (size_t)q * 24;
        const float4* r4 = (const float4*)rec;
        float4 h0 = r4[0], h1 = r4[1], h2 = r4[2], h3 = r4[3];
        float4 y  = r4[4];
        float rc  = rec[20];
        int j = __float_as_int(rec[21]);

        const float* em = embed + (size_t)j * 64;
        float sj = em[f];
        float vx = em[16 + f];
        float vy = em[32 + f];
        float vz = em[48 + f];

        float w0a = rc*b0a, w0b = rc*b0b, w1a = rc*b1a, w1b = rc*b1b;
        float h[16] = {h0.x,h0.y,h0.z,h0.w, h1.x,h1.y,h1.z,h1.w,
                       h2.x,h2.y,h2.z,h2.w, h3.x,h3.y,h3.z,h3.w};
#pragma unroll
        for (int k = 0; k < 16; k++) {
            w0a += h[k] * wga[k];
            w0b += h[k] * wgb[k];
            w1a += h[k] * wgc[k];
            w1b += h[k] * wgd[k];
        }

        aa += sj * y.x * w0a;
        ab += (vx*y.y + vy*y.z + vz*y.w) * w0b;
        float sw = sj * w1a;
        A1a0 += sw * y.y;
        A1a1 += sw * y.z;
        A1a2 += sw * y.w;
        float yw = y.x * w1b;
        A1b0 += vx * yw;
        A1b1 += vy * yw;
        A1b2 += vz * yw;
    }

    const float is3 = 0.5773502691896258f;   // 1/sqrt(3)
    float* o = acc + (size_t)node * 128;
    o[f]       = aa;
    o[16 + f]  = ab * is3;
    o[32 + f]  = A1a0;
    o[48 + f]  = A1a1;
    o[64 + f]  = A1a2;
    o[80 + f]  = A1b0;
    o[96 + f]  = A1b1;
    o[112 + f] = A1b2;
}

// ---------------- node output ----------------
// 2 threads per node: role 0 = scalar path (n0->s2->s3), role 1 = vector path
// (n1->v2->v3, all 3 d-planes). Roles split at wave granularity (t>>7).
// Weights read via uniform (scalar) loads -> SGPRs; per-node data in VGPRs.
// No LDS at all.
__global__ __launch_bounds__(256) void out_kernel(
    const float* __restrict__ acc,      // (N,128) planar
    const float* __restrict__ W2s,      // (32,64)
    const float* __restrict__ W2v,      // (32,32)
    const float* __restrict__ W3s,      // (64,64)
    const float* __restrict__ W3v,      // (32,32)
    float* __restrict__ out)            // (N,160)
{
    int t = threadIdx.x;
    int role = t >> 7;                    // waves 0-1: scalar, waves 2-3: vector
    int n = blockIdx.x * 128 + (t & 127);
    const float* a = acc + (size_t)n * 128;
    float* o = out + (size_t)n * 160;
    const float is32 = 0.17677669529663688f;

    if (role == 0) {
        // ---- scalar path ----
        float n0[32];
#pragma unroll
        for (int q = 0; q < 8; q++) ((float4*)n0)[q] = ((const float4*)a)[q];

        float s2[64];
#pragma unroll
        for (int c0 = 0; c0 < 64; c0 += 16) {
            float t16[16];
#pragma unroll
            for (int u = 0; u < 16; u++) t16[u] = 0.f;
#pragma unroll
            for (int k = 0; k < 32; k++) {
                float nk = n0[k];
#pragma unroll
                for (int u = 0; u < 16; u++)
                    t16[u] += nk * W2s[k*64 + c0 + u];
            }
#pragma unroll
            for (int u = 0; u < 16; u++) s2[c0+u] = sspf(t16[u] * is32);
        }

#pragma unroll
        for (int c0 = 0; c0 < 64; c0 += 16) {
            float t16[16];
#pragma unroll
            for (int u = 0; u < 16; u++) t16[u] = 0.f;
#pragma unroll
            for (int k = 0; k < 64; k++) {
                float sk = s2[k];
#pragma unroll
                for (int u = 0; u < 16; u++)
                    t16[u] += sk * W3s[k*64 + c0 + u];
            }
            float4 r0 = {t16[0]*0.125f,  t16[1]*0.125f,  t16[2]*0.125f,  t16[3]*0.125f};
            float4 r1 = {t16[4]*0.125f,  t16[5]*0.125f,  t16[6]*0.125f,  t16[7]*0.125f};
            float4 r2 = {t16[8]*0.125f,  t16[9]*0.125f,  t16[10]*0.125f, t16[11]*0.125f};
            float4 r3 = {t16[12]*0.125f, t16[13]*0.125f, t16[14]*0.125f, t16[15]*0.125f};
            ((float4*)(o + c0))[0] = r0;
            ((float4*)(o + c0))[1] = r1;
            ((float4*)(o + c0))[2] = r2;
            ((float4*)(o + c0))[3] = r3;
        }
    } else {
        // ---- vector path ----
        float v3buf[96];
#pragma unroll
        for (int d = 0; d < 3; d++) {
            float na[16], nb[16];
            const float4* pa = (const float4*)(a + 32 + 16*d);
            const float4* pb = (const float4*)(a + 80 + 16*d);
#pragma unroll
            for (int q = 0; q < 4; q++) { ((float4*)na)[q] = pa[q]; ((float4*)nb)[q] = pb[q]; }

            float v2[32];
#pragma unroll
            for (int c0 = 0; c0 < 32; c0 += 16) {
                float t16[16];
#pragma unroll
                for (int u = 0; u < 16; u++) t16[u] = 0.f;
#pragma unroll
                for (int f = 0; f < 16; f++) {
                    float fa = na[f], fbv = nb[f];
#pragma unroll
                    for (int u = 0; u < 16; u++) {
                        t16[u] += fa  * W2v[f*32 + c0 + u];
                        t16[u] += fbv * W2v[(16+f)*32 + c0 + u];
                    }
                }
#pragma unroll
                for (int u = 0; u < 16; u++) v2[c0+u] = t16[u] * is32;
            }

#pragma unroll
            for (int e0 = 0; e0 < 32; e0 += 16) {
                float t16[16];
#pragma unroll
                for (int u = 0; u < 16; u++) t16[u] = 0.f;
#pragma unroll
                for (int c = 0; c < 32; c++) {
                    float vc = v2[c];
#pragma unroll
                    for (int u = 0; u < 16; u++)
                        t16[u] += vc * W3v[c*32 + e0 + u];
                }
#pragma unroll
                for (int u = 0; u < 16; u++) v3buf[(e0+u)*3 + d] = t16[u] * is32;
            }
        }
        float4* ov = (float4*)(o + 64);
#pragma unroll
        for (int q = 0; q < 24; q++) ov[q] = ((float4*)v3buf)[q];
    }
}

extern "C" void kernel_launch(void* const* d_in, const int* in_sizes, int n_in,
                              void* d_out, int out_size, void* d_ws, size_t ws_size,
                              hipStream_t stream) {
    const float* x     = (const float*)d_in[0];
    const float* f_ij  = (const float*)d_in[1];
    const float* rcut  = (const float*)d_in[2];
    const float* Yr    = (const float*)d_in[3];
    const float* W1s   = (const float*)d_in[4];
    const float* W1v   = (const float*)d_in[5];
    const float* mW1   = (const float*)d_in[6];
    const float* mb1   = (const float*)d_in[7];
    const float* mW2   = (const float*)d_in[8];
    const float* mb2   = (const float*)d_in[9];
    const float* W2s   = (const float*)d_in[10];
    const float* W2v   = (const float*)d_in[11];
    const float* W3s   = (const float*)d_in[12];
    const float* W3v   = (const float*)d_in[13];
    const int*   idx_i = (const int*)d_in[14];
    const int*   idx_j = (const int*)d_in[15];
    float* out = (float*)d_out;

    // workspace layout (floats)
    float* fws   = (float*)d_ws;
    float* embed = fws;                                  // N*64
    float* acc   = embed + (size_t)NN * 64;              // N*128
    float* epack = acc   + (size_t)NN * 128;             // E*24
    int* ibase   = (int*)(epack + (size_t)NE * 24);
    int* counts  = ibase;                                // N
    int* start   = counts + NN;                          // N+1
    int* cursor  = start + NN + 1;                       // N

    hipMemsetAsync(counts, 0, (size_t)NN * sizeof(int), stream);
    hist_kernel<<<NE/256, 256, 0, stream>>>(idx_i, counts);
    scan_kernel<<<1, 1024, 0, stream>>>(counts, start, cursor);
    pack_kernel<<<NE/256, 256, 0, stream>>>(f_ij, rcut, Yr, idx_i, idx_j,
                                            mW1, mb1, cursor, epack);
    embed_kernel<<<NN/256, 256, 0, stream>>>(x, W1s, W1v, embed);
    nodeagg_kernel<<<(NN*16)/256, 256, 0, stream>>>(embed, epack, start, mW2, mb2, acc);
    out_kernel<<<NN/128, 256, 0, stream>>>(acc, W2s, W2v, W3s, W3v, out);
}

// Round 7
// 358.833 us; speedup vs baseline: 1.1795x; 1.1795x over previous
//
#include <hip/hip_runtime.h>
#include <math.h>

#define NN 32768
#define NE 524288

__device__ __forceinline__ float sspf(float x) {
    float r = fmaxf(x, 0.0f) + log1pf(expf(-fabsf(x)));
    return r - 0.69314718055994530942f;
}

// ---------------- CSR build ----------------
__global__ __launch_bounds__(256) void hist_kernel(
    const int* __restrict__ idx_i, int* __restrict__ counts)
{
    int e = blockIdx.x * 256 + threadIdx.x;
    atomicAdd(&counts[idx_i[e]], 1);
}

// single block, 1024 threads, 32 counts each; writes start[0..NN] and cursor
__global__ __launch_bounds__(1024) void scan_kernel(
    const int* __restrict__ counts, int* __restrict__ start, int* __restrict__ cursor)
{
    __shared__ int tmp[1024];
    int tid = threadIdx.x;
    int base = tid * 32;
    int local[32];
    int sum = 0;
    const int4* c4 = (const int4*)(counts + base);
#pragma unroll
    for (int q = 0; q < 8; q++) {
        int4 v = c4[q];
        local[q*4+0] = sum; sum += v.x;
        local[q*4+1] = sum; sum += v.y;
        local[q*4+2] = sum; sum += v.z;
        local[q*4+3] = sum; sum += v.w;
    }
    tmp[tid] = sum;
    __syncthreads();
    for (int off = 1; off < 1024; off <<= 1) {
        int v = 0;
        if (tid >= off) v = tmp[tid - off];
        __syncthreads();
        if (tid >= off) tmp[tid] += v;
        __syncthreads();
    }
    int excl = tmp[tid] - sum;
#pragma unroll
    for (int k = 0; k < 32; k++) {
        int s = excl + local[k];
        start[base + k] = s;
        cursor[base + k] = s;
    }
    if (tid == 1023) start[NN] = tmp[1023];
}

// ---------------- pack: fused fill + filter-MLP-layer-1 ----------------
// record (24 floats): [0:16)=h*rc, [16:20)=Yr, [20]=rc, [21]=j(bits), [22:24)=pad
__global__ __launch_bounds__(256) void pack_kernel(
    const float* __restrict__ f_ij,     // (E,32)
    const float* __restrict__ rcut_ij,  // (E,)
    const float* __restrict__ Yr,       // (E,4)
    const int*   __restrict__ idx_i,
    const int*   __restrict__ idx_j,
    const float* __restrict__ mW1,      // (32,16)
    const float* __restrict__ mb1,      // (16,)
    int* __restrict__ cursor,
    float* __restrict__ epack)
{
    __shared__ float sW1[512];
    __shared__ float sb1[16];
    int t = threadIdx.x;
    for (int k = t; k < 512; k += 256) sW1[k] = mW1[k];
    if (t < 16) sb1[t] = mb1[t];
    __syncthreads();

    int e = blockIdx.x * 256 + t;
    float h[16];
#pragma unroll
    for (int f = 0; f < 16; f++) h[f] = sb1[f];
    const float4* frow = (const float4*)(f_ij + (size_t)e * 32);
#pragma unroll
    for (int rq = 0; rq < 8; rq++) {
        float4 fv = frow[rq];
        int r = rq * 4;
#pragma unroll
        for (int f = 0; f < 16; f++)
            h[f] += fv.x * sW1[(r+0)*16+f] + fv.y * sW1[(r+1)*16+f]
                  + fv.z * sW1[(r+2)*16+f] + fv.w * sW1[(r+3)*16+f];
    }
    float rc = rcut_ij[e];
#pragma unroll
    for (int f = 0; f < 16; f++) h[f] = sspf(h[f]) * rc;

    int i = idx_i[e];
    int j = idx_j[e];
    float4 y = ((const float4*)Yr)[e];
    int slot = atomicAdd(&cursor[i], 1);

    float* rec = epack + (size_t)slot * 24;
    float4* r4 = (float4*)rec;
#pragma unroll
    for (int q = 0; q < 4; q++) r4[q] = ((float4*)h)[q];
    r4[4] = y;
    rec[20] = rc;
    rec[21] = __int_as_float(j);
    rec[22] = 0.f;
    rec[23] = 0.f;
}

// ---------------- node embedding ----------------
// planar output layout: [0:16)=s1, [16:32)=v1x, [32:48)=v1y, [48:64)=v1z
__global__ __launch_bounds__(256) void embed_kernel(
    const float* __restrict__ x,
    const float* __restrict__ W1s,   // (64,16)
    const float* __restrict__ W1v,   // (32,16)
    float* __restrict__ embed)
{
    __shared__ float sWs[1024];
    __shared__ float sWv[512];
    int t = threadIdx.x;
    for (int k = t; k < 1024; k += 256) sWs[k] = W1s[k];
    for (int k = t; k < 512;  k += 256) sWv[k] = W1v[k];
    __syncthreads();

    int n = blockIdx.x * 256 + t;
    const float* xr = x + (size_t)n * 160;

    float s1[16];
#pragma unroll
    for (int f = 0; f < 16; f++) s1[f] = 0.f;
#pragma unroll
    for (int cq = 0; cq < 16; cq++) {
        float4 sv = ((const float4*)xr)[cq];
        int c = cq * 4;
#pragma unroll
        for (int f = 0; f < 16; f++) {
            s1[f] += sv.x * sWs[(c+0)*16+f] + sv.y * sWs[(c+1)*16+f]
                   + sv.z * sWs[(c+2)*16+f] + sv.w * sWs[(c+3)*16+f];
        }
    }

    float v1[48];
#pragma unroll
    for (int k = 0; k < 48; k++) v1[k] = 0.f;
#pragma unroll
    for (int q = 0; q < 24; q++) {
        float4 vv = ((const float4*)(xr + 64))[q];
        float vals[4] = {vv.x, vv.y, vv.z, vv.w};
#pragma unroll
        for (int u = 0; u < 4; u++) {
            int m = q * 4 + u;
            int c = m / 3, d = m % 3;
            float val = vals[u];
#pragma unroll
            for (int f = 0; f < 16; f++)
                v1[f*3+d] += val * sWv[c*16+f];
        }
    }

    float ob[64];
    const float is32 = 0.17677669529663688f;
#pragma unroll
    for (int f = 0; f < 16; f++) {
        ob[f]      = s1[f] * 0.125f;
        ob[16 + f] = v1[f*3+0] * is32;
        ob[32 + f] = v1[f*3+1] * is32;
        ob[48 + f] = v1[f*3+2] * is32;
    }

    float4* eo = (float4*)(embed + (size_t)n * 64);
#pragma unroll
    for (int q = 0; q < 16; q++) eo[q] = ((float4*)ob)[q];
}

// ---------------- node-centric aggregation ----------------
// 16 threads per node; thread handles a single f. w-matmul fully partitioned.
// acc planar layout per node:
// [0:16)=n0a, [16:32)=n0b, [32:48)=n1a_x, [48:64)=n1a_y, [64:80)=n1a_z,
// [80:96)=n1b_x, [96:112)=n1b_y, [112:128)=n1b_z
__global__ __launch_bounds__(256) void nodeagg_kernel(
    const float* __restrict__ embed,   // (N,64) planar
    const float* __restrict__ epack,   // (E,24) CSR-ordered records
    const int*   __restrict__ start,   // (N+1,)
    const float* __restrict__ mW2,     // (16,96)
    const float* __restrict__ mb2,     // (96,)
    float* __restrict__ acc)           // (N,128) planar
{
    __shared__ float sW2[1024];        // sW2[k*64+c] = mW2[k*96+c], c<64
    int t = threadIdx.x;
    for (int k = t; k < 1024; k += 256)
        sW2[k] = mW2[(k >> 6) * 96 + (k & 63)];
    __syncthreads();

    int gid = blockIdx.x * 256 + t;
    int node = gid >> 4;
    int f = gid & 15;

    float wga[16], wgb[16], wgc[16], wgd[16];
#pragma unroll
    for (int k = 0; k < 16; k++) {
        wga[k] = sW2[k*64 + f];
        wgb[k] = sW2[k*64 + 16 + f];
        wgc[k] = sW2[k*64 + 32 + f];
        wgd[k] = sW2[k*64 + 48 + f];
    }
    float b0a = mb2[f], b0b = mb2[16+f], b1a = mb2[32+f], b1b = mb2[48+f];

    float aa = 0.f, ab = 0.f;
    float A1a0 = 0.f, A1a1 = 0.f, A1a2 = 0.f;
    float A1b0 = 0.f, A1b1 = 0.f, A1b2 = 0.f;

    int s0 = start[node];
    int s1 = start[node+1];

    for (int q = s0; q < s1; q++) {
        const float* rec = epack + (size_t)q * 24;
        const float4* r4 = (const float4*)rec;
        float4 h0 = r4[0], h1 = r4[1], h2 = r4[2], h3 = r4[3];
        float4 y  = r4[4];
        float rc  = rec[20];
        int j = __float_as_int(rec[21]);

        const float* em = embed + (size_t)j * 64;
        float sj = em[f];
        float vx = em[16 + f];
        float vy = em[32 + f];
        float vz = em[48 + f];

        float w0a = rc*b0a, w0b = rc*b0b, w1a = rc*b1a, w1b = rc*b1b;
        float h[16] = {h0.x,h0.y,h0.z,h0.w, h1.x,h1.y,h1.z,h1.w,
                       h2.x,h2.y,h2.z,h2.w, h3.x,h3.y,h3.z,h3.w};
#pragma unroll
        for (int k = 0; k < 16; k++) {
            w0a += h[k] * wga[k];
            w0b += h[k] * wgb[k];
            w1a += h[k] * wgc[k];
            w1b += h[k] * wgd[k];
        }

        aa += sj * y.x * w0a;
        ab += (vx*y.y + vy*y.z + vz*y.w) * w0b;
        float sw = sj * w1a;
        A1a0 += sw * y.y;
        A1a1 += sw * y.z;
        A1a2 += sw * y.w;
        float yw = y.x * w1b;
        A1b0 += vx * yw;
        A1b1 += vy * yw;
        A1b2 += vz * yw;
    }

    const float is3 = 0.5773502691896258f;   // 1/sqrt(3)
    float* o = acc + (size_t)node * 128;
    o[f]       = aa;
    o[16 + f]  = ab * is3;
    o[32 + f]  = A1a0;
    o[48 + f]  = A1a1;
    o[64 + f]  = A1a2;
    o[80 + f]  = A1b0;
    o[96 + f]  = A1b1;
    o[112 + f] = A1b2;
}

// ---------------- node output ----------------
// 64 nodes per block (lane = node), 4 wave-specialized roles:
// wave 0: s-chain cols 0-31; wave 1: s-chain cols 32-63
// wave 2: v-chain (d=0 all cols, d=1 cols 0-15); wave 3: (d=1 cols 16-31, d=2 all)
// Weight columns are wave-uniform (readfirstlane) -> scalar s_load broadcasts.
// Intermediates in LDS with +1 pad (2-way bank alias only, free).

__device__ __forceinline__ void v2_seg32(const float* a, int d, int cb,
    const float* __restrict__ W2v, float* V2, int ln)
{
    cb = __builtin_amdgcn_readfirstlane(cb);
    const float is32 = 0.17677669529663688f;
    float na[16], nb[16];
    const float4* pa = (const float4*)(a + 32 + 16*d);
    const float4* pb = (const float4*)(a + 80 + 16*d);
#pragma unroll
    for (int q = 0; q < 4; q++) { ((float4*)na)[q] = pa[q]; ((float4*)nb)[q] = pb[q]; }
    float tacc[32];
#pragma unroll
    for (int c = 0; c < 32; c++) tacc[c] = 0.f;
#pragma unroll
    for (int f = 0; f < 16; f++) {
        float fa = na[f], fb = nb[f];
#pragma unroll
        for (int c = 0; c < 32; c++)
            tacc[c] += fa * W2v[f*32 + cb + c] + fb * W2v[(16+f)*32 + cb + c];
    }
    float* row = V2 + (d*64 + ln) * 33 + cb;
#pragma unroll
    for (int c = 0; c < 32; c++) row[c] = tacc[c] * is32;
}

__device__ __forceinline__ void v2_seg16(const float* a, int d, int cb,
    const float* __restrict__ W2v, float* V2, int ln)
{
    cb = __builtin_amdgcn_readfirstlane(cb);
    const float is32 = 0.17677669529663688f;
    float na[16], nb[16];
    const float4* pa = (const float4*)(a + 32 + 16*d);
    const float4* pb = (const float4*)(a + 80 + 16*d);
#pragma unroll
    for (int q = 0; q < 4; q++) { ((float4*)na)[q] = pa[q]; ((float4*)nb)[q] = pb[q]; }
    float tacc[16];
#pragma unroll
    for (int c = 0; c < 16; c++) tacc[c] = 0.f;
#pragma unroll
    for (int f = 0; f < 16; f++) {
        float fa = na[f], fb = nb[f];
#pragma unroll
        for (int c = 0; c < 16; c++)
            tacc[c] += fa * W2v[f*32 + cb + c] + fb * W2v[(16+f)*32 + cb + c];
    }
    float* row = V2 + (d*64 + ln) * 33 + cb;
#pragma unroll
    for (int c = 0; c < 16; c++) row[c] = tacc[c] * is32;
}

__device__ __forceinline__ void v3_seg32(float* o, int d, int cb,
    const float* __restrict__ W3v, const float* V2, int ln)
{
    cb = __builtin_amdgcn_readfirstlane(cb);
    const float is32 = 0.17677669529663688f;
    float tacc[32];
#pragma unroll
    for (int c = 0; c < 32; c++) tacc[c] = 0.f;
    const float* row = V2 + (d*64 + ln) * 33;
#pragma unroll
    for (int k = 0; k < 32; k++) {
        float vk = row[k];
#pragma unroll
        for (int c = 0; c < 32; c++) tacc[c] += vk * W3v[k*32 + cb + c];
    }
#pragma unroll
    for (int c = 0; c < 32; c++) o[64 + (cb+c)*3 + d] = tacc[c] * is32;
}

__device__ __forceinline__ void v3_seg16(float* o, int d, int cb,
    const float* __restrict__ W3v, const float* V2, int ln)
{
    cb = __builtin_amdgcn_readfirstlane(cb);
    const float is32 = 0.17677669529663688f;
    float tacc[16];
#pragma unroll
    for (int c = 0; c < 16; c++) tacc[c] = 0.f;
    const float* row = V2 + (d*64 + ln) * 33;
#pragma unroll
    for (int k = 0; k < 32; k++) {
        float vk = row[k];
#pragma unroll
        for (int c = 0; c < 16; c++) tacc[c] += vk * W3v[k*32 + cb + c];
    }
#pragma unroll
    for (int c = 0; c < 16; c++) o[64 + (cb+c)*3 + d] = tacc[c] * is32;
}

__global__ __launch_bounds__(256) void out_kernel(
    const float* __restrict__ acc,      // (N,128) planar
    const float* __restrict__ W2s,      // (32,64)
    const float* __restrict__ W2v,      // (32,32)
    const float* __restrict__ W3s,      // (64,64)
    const float* __restrict__ W3v,      // (32,32)
    float* __restrict__ out)            // (N,160)
{
    __shared__ float S2[64*65];   // S2[ln*65 + c], c<64
    __shared__ float V2[3*64*33]; // V2[(d*64+ln)*33 + c], c<32
    int t = threadIdx.x;
    int w = t >> 6, ln = t & 63;
    int node = blockIdx.x * 64 + ln;
    const float* a = acc + (size_t)node * 128;
    float* o = out + (size_t)node * 160;
    const float is32 = 0.17677669529663688f;

    if (w < 2) {
        int cb = __builtin_amdgcn_readfirstlane(w * 32);
        float n0r[32];
#pragma unroll
        for (int q = 0; q < 8; q++) ((float4*)n0r)[q] = ((const float4*)a)[q];
        float tacc[32];
#pragma unroll
        for (int c = 0; c < 32; c++) tacc[c] = 0.f;
#pragma unroll
        for (int k = 0; k < 32; k++) {
            float nk = n0r[k];
#pragma unroll
            for (int c = 0; c < 32; c++) tacc[c] += nk * W2s[k*64 + cb + c];
        }
        float* row = S2 + ln*65 + cb;
#pragma unroll
        for (int c = 0; c < 32; c++) row[c] = sspf(tacc[c] * is32);
    } else if (w == 2) {
        v2_seg32(a, 0, 0,  W2v, V2, ln);
        v2_seg16(a, 1, 0,  W2v, V2, ln);
    } else {
        v2_seg16(a, 1, 16, W2v, V2, ln);
        v2_seg32(a, 2, 0,  W2v, V2, ln);
    }
    __syncthreads();
    if (w < 2) {
        int cb = __builtin_amdgcn_readfirstlane(w * 32);
        float tacc[32];
#pragma unroll
        for (int c = 0; c < 32; c++) tacc[c] = 0.f;
        const float* row = S2 + ln*65;
#pragma unroll
        for (int k = 0; k < 64; k++) {
            float sk = row[k];
#pragma unroll
            for (int c = 0; c < 32; c++) tacc[c] += sk * W3s[k*64 + cb + c];
        }
#pragma unroll
        for (int q = 0; q < 8; q++) {
            float4 r = {tacc[q*4+0]*0.125f, tacc[q*4+1]*0.125f,
                        tacc[q*4+2]*0.125f, tacc[q*4+3]*0.125f};
            ((float4*)(o + cb))[q] = r;
        }
    } else if (w == 2) {
        v3_seg32(o, 0, 0,  W3v, V2, ln);
        v3_seg16(o, 1, 0,  W3v, V2, ln);
    } else {
        v3_seg16(o, 1, 16, W3v, V2, ln);
        v3_seg32(o, 2, 0,  W3v, V2, ln);
    }
}

extern "C" void kernel_launch(void* const* d_in, const int* in_sizes, int n_in,
                              void* d_out, int out_size, void* d_ws, size_t ws_size,
                              hipStream_t stream) {
    const float* x     = (const float*)d_in[0];
    const float* f_ij  = (const float*)d_in[1];
    const float* rcut  = (const float*)d_in[2];
    const float* Yr    = (const float*)d_in[3];
    const float* W1s   = (const float*)d_in[4];
    const float* W1v   = (const float*)d_in[5];
    const float* mW1   = (const float*)d_in[6];
    const float* mb1   = (const float*)d_in[7];
    const float* mW2   = (const float*)d_in[8];
    const float* mb2   = (const float*)d_in[9];
    const float* W2s   = (const float*)d_in[10];
    const float* W2v   = (const float*)d_in[11];
    const float* W3s   = (const float*)d_in[12];
    const float* W3v   = (const float*)d_in[13];
    const int*   idx_i = (const int*)d_in[14];
    const int*   idx_j = (const int*)d_in[15];
    float* out = (float*)d_out;

    // workspace layout (floats)
    float* fws   = (float*)d_ws;
    float* embed = fws;                                  // N*64
    float* acc   = embed + (size_t)NN * 64;              // N*128
    float* epack = acc   + (size_t)NN * 128;             // E*24
    int* ibase   = (int*)(epack + (size_t)NE * 24);
    int* counts  = ibase;                                // N
    int* start   = counts + NN;                          // N+1
    int* cursor  = start + NN + 1;                       // N

    hipMemsetAsync(counts, 0, (size_t)NN * sizeof(int), stream);
    hist_kernel<<<NE/256, 256, 0, stream>>>(idx_i, counts);
    scan_kernel<<<1, 1024, 0, stream>>>(counts, start, cursor);
    pack_kernel<<<NE/256, 256, 0, stream>>>(f_ij, rcut, Yr, idx_i, idx_j,
                                            mW1, mb1, cursor, epack);
    embed_kernel<<<NN/256, 256, 0, stream>>>(x, W1s, W1v, embed);
    nodeagg_kernel<<<(NN*16)/256, 256, 0, stream>>>(embed, epack, start, mW2, mb2, acc);
    out_kernel<<<NN/64, 256, 0, stream>>>(acc, W2s, W2v, W3s, W3v, out);
}